// Round 5
// baseline (180.243 us; speedup 1.0000x reference)
//
#include <hip/hip_runtime.h>
#include <hip/hip_bf16.h>

#define NPER 24
#define B_ 32
#define N_ 1024
#define F_ 128
#define H_ 64
#define E_ 16

typedef __attribute__((ext_vector_type(8))) short short8;
typedef __attribute__((ext_vector_type(4))) float f32x4;

static __device__ __forceinline__ unsigned short f2bf(float x) {
    union { float f; unsigned u; } v; v.f = x;
    unsigned r = v.u + 0x7fffu + ((v.u >> 16) & 1u);   // RNE
    return (unsigned short)(r >> 16);
}
static __device__ __forceinline__ float bf2f(unsigned short h) {
    union { unsigned u; float f; } v; v.u = ((unsigned)h) << 16; return v.f;
}
static __device__ __forceinline__ unsigned short f2bf_hw(float x) {
    __hip_bfloat16 h = __float2bfloat16(x);
    return *(unsigned short*)&h;
}

// ---------------------------------------------------------------------------
// P1: env encoder fused into src/tgt bf16 conversion for all 24 periods.
// ---------------------------------------------------------------------------
__global__ __launch_bounds__(256) void prep_srctgt(
    const float* __restrict__ src_emb, const float* __restrict__ tgt_emb,
    const float* __restrict__ env_features, const float* __restrict__ env_W,
    const float* __restrict__ env_b,
    unsigned short* __restrict__ src_bf, unsigned short* __restrict__ tgt_bf)
{
    const int idx = blockIdx.x * 256 + threadIdx.x;   // 0..65535
    const int n = idx >> 6, h = idx & 63;
    float e = env_b[h];
#pragma unroll
    for (int k = 0; k < E_; ++k)
        e = fmaf(env_features[n * E_ + k], env_W[k * H_ + h], e);
    e = fmaxf(e, 0.f);
#pragma unroll 4
    for (int p = 0; p < NPER; ++p) {
        const size_t off = (size_t)p * (N_ * H_) + idx;
        src_bf[off] = f2bf(src_emb[off] + e);
        tgt_bf[off] = f2bf(tgt_emb[off] + e);
    }
}

// ---------------------------------------------------------------------------
// P2: adj -> bf16 (blocks 0..1023) ; W/rW transpose -> bf16 (blocks 1024..1151)
// ---------------------------------------------------------------------------
__global__ __launch_bounds__(256) void prep_cvt(
    const float* __restrict__ adj, const float* __restrict__ W,
    const float* __restrict__ rW,
    unsigned short* __restrict__ adj_bf, unsigned short* __restrict__ Wt,
    unsigned short* __restrict__ rWt)
{
    const int bid = blockIdx.x;
    if (bid < 1024) {
        const size_t i = ((size_t)bid * 256 + threadIdx.x) * 4;
        float4 v = *(const float4*)(adj + i);
        ushort4 o;
        o.x = f2bf(v.x); o.y = f2bf(v.y); o.z = f2bf(v.z); o.w = f2bf(v.w);
        *(ushort4*)(adj_bf + i) = o;
    } else {
        const int idx = (bid - 1024) * 256 + threadIdx.x;   // 0..32767
        const int which = idx >> 14, j = idx & 16383;
        const int f = j >> 7, d = j & 127;
        if (which == 0) Wt[f * 128 + d]  = f2bf(W[d * 128 + f]);
        else            rWt[f * 128 + d] = f2bf(rW[d * 128 + f]);
    }
}

// ---------------------------------------------------------------------------
// K5: support^T (swapped GEMM) + residual, both bf16 out, MFMA. [verified]
// ---------------------------------------------------------------------------
__global__ __launch_bounds__(256) void gemm2_mfma(
    const float* __restrict__ x,               // [B*N][128] fp32
    const unsigned short* __restrict__ Wt,     // [128f][128d]
    const unsigned short* __restrict__ rWt,    // [128f][128d]
    const float* __restrict__ rb,              // [128]
    unsigned short* __restrict__ supT,         // [B][128f][1024m]
    unsigned short* __restrict__ resid)        // [B*N][128]
{
    const int t = threadIdx.x, w = t >> 6, l = t & 63;
    const int ln = l & 15, kb = l >> 4;
    const int mblk = w >> 1, fhalf = w & 1;
    const int row0 = blockIdx.x * 32;
    const int b   = row0 >> 10;
    const int mg0 = row0 & 1023;

    const float* xrow = x + (size_t)(row0 + mblk * 16 + ln) * 128;
    short8 xa[4];
#pragma unroll
    for (int k = 0; k < 4; ++k) {
        float4 v0 = *(const float4*)(xrow + k * 32 + kb * 8);
        float4 v1 = *(const float4*)(xrow + k * 32 + kb * 8 + 4);
        short8 s;
        s[0] = (short)f2bf(v0.x); s[1] = (short)f2bf(v0.y);
        s[2] = (short)f2bf(v0.z); s[3] = (short)f2bf(v0.w);
        s[4] = (short)f2bf(v1.x); s[5] = (short)f2bf(v1.y);
        s[6] = (short)f2bf(v1.z); s[7] = (short)f2bf(v1.w);
        xa[k] = s;
    }

    f32x4 accS[4], accR[4];
#pragma unroll
    for (int i = 0; i < 4; ++i) { accS[i] = (f32x4){0,0,0,0}; accR[i] = (f32x4){0,0,0,0}; }

#pragma unroll
    for (int k = 0; k < 4; ++k) {
#pragma unroll
        for (int fb = 0; fb < 4; ++fb) {
            int fr = (fhalf * 4 + fb) * 16 + ln;
            short8 wa = *(const short8*)(Wt  + (size_t)fr * 128 + k * 32 + kb * 8);
            short8 wb = *(const short8*)(rWt + (size_t)fr * 128 + k * 32 + kb * 8);
            accS[fb] = __builtin_amdgcn_mfma_f32_16x16x32_bf16(wa, xa[k], accS[fb], 0, 0, 0);
            accR[fb] = __builtin_amdgcn_mfma_f32_16x16x32_bf16(xa[k], wb, accR[fb], 0, 0, 0);
        }
    }

#pragma unroll
    for (int fb = 0; fb < 4; ++fb) {
        int m = mg0 + mblk * 16 + ln;
#pragma unroll
        for (int i = 0; i < 4; ++i) {
            int f = (fhalf * 4 + fb) * 16 + kb * 4 + i;
            supT[((size_t)b * 128 + f) * 1024 + m] = f2bf(accS[fb][i]);
        }
    }
#pragma unroll
    for (int fb = 0; fb < 4; ++fb) {
        int f = (fhalf * 4 + fb) * 16 + ln;
        float rbf = rb[f];
#pragma unroll
        for (int i = 0; i < 4; ++i) {
            size_t row = (size_t)row0 + mblk * 16 + kb * 4 + i;
            resid[row * 128 + f] = f2bf(fmaxf(accR[fb][i] + rbf, 0.f));
        }
    }
}

// ---------------------------------------------------------------------------
// K6: fused scores -> relu*adj -> conv -> epilogue.  BARRIER-FREE main loop.
// 256 threads / 4 waves; wave w: n-strip ns=w>>1 (16 rows), f-half fh=w&1
// (64 f). Each wave fully independent: swapped score MFMA (C cols = n) ->
// mask in regs -> wave-private padded LDS tile (stride 36 shorts, parity
// double-buffered) -> conv A-frags via ds_read_b64 pairs -> conv MFMA.
// tgt/adj register-prefetched 2 chunks (32 m each) ahead; supT loads issued
// at chunk start. No __syncthreads anywhere in the loop.
// ---------------------------------------------------------------------------
__global__ __launch_bounds__(256, 4) void conv_mfma(
    const unsigned short* __restrict__ src_bf,  // [P][N][64]
    const unsigned short* __restrict__ tgt_bf,  // [P][N][64]
    const unsigned short* __restrict__ adj_bf,  // [N][N]
    const unsigned short* __restrict__ supT,    // [B][128][1024]
    const unsigned short* __restrict__ resid,   // [B*N][128]
    const float* __restrict__ bias,             // [128]
    const int* __restrict__ cyc,                // [B]
    float* __restrict__ out)                    // [B][N][128]
{
    __shared__ unsigned short s_a[4][2][16 * 36] __attribute__((aligned(16)));

    // chunked XCD swizzle (r4-verified: FETCH 48.9 -> 20.8 MB)
    const int i = blockIdx.x;                    // 0..1023
    const int work = (i & 7) * 128 + (i >> 3);
    const int b  = work >> 5;
    const int n0 = (work & 31) * 32;

    const int t = threadIdx.x, w = t >> 6, l = t & 63;
    const int ln = l & 15, kb = l >> 4;
    const int ns = w >> 1, fh = w & 1;
    const int p = ((cyc[b] % NPER) + NPER) % NPER;

    unsigned short* sa_w = &s_a[w][0][0];

    // src as score B-operand: col = ln -> n row n0 + ns*16 + ln
    const unsigned short* srow = src_bf + ((size_t)p * N_ + n0 + ns * 16 + ln) * H_;
    const short8 sb0 = *(const short8*)(srow + kb * 8);
    const short8 sb1 = *(const short8*)(srow + 32 + kb * 8);

    const unsigned short* tbase = tgt_bf + (size_t)p * N_ * H_;
    const unsigned short* supf  = supT + ((size_t)b * 128 + fh * 64 + ln) * (size_t)N_;
    const unsigned short* adjp  = adj_bf + (size_t)(n0 + ns * 16 + ln) * N_;

    f32x4 acc[4];
#pragma unroll
    for (int q = 0; q < 4; ++q) acc[q] = (f32x4){0, 0, 0, 0};

    // tgt as score A-operand: row = ln -> m row m0 + mt*16 + ln
    auto loadT = [&](int m0, short8 (&tb)[4], ushort4 (&av)[2]) {
#pragma unroll
        for (int mt = 0; mt < 2; ++mt) {
            const unsigned short* trow = tbase + (size_t)(m0 + mt * 16 + ln) * H_;
            tb[mt * 2]     = *(const short8*)(trow + kb * 8);
            tb[mt * 2 + 1] = *(const short8*)(trow + 32 + kb * 8);
            av[mt] = *(const ushort4*)(adjp + m0 + mt * 16 + kb * 4);
        }
    };

    auto chunk = [&](int m0, short8 (&tb)[4], ushort4 (&av)[2], int par, int m0next) {
        // conv B-frags for this chunk (issue first; consumed ~400cy later)
        short8 bs0 = *(const short8*)(supf + 0 * 16 * N_ + m0 + kb * 8);
        short8 bs1 = *(const short8*)(supf + 1 * 16 * N_ + m0 + kb * 8);
        short8 bs2 = *(const short8*)(supf + 2 * 16 * N_ + m0 + kb * 8);
        short8 bs3 = *(const short8*)(supf + 3 * 16 * N_ + m0 + kb * 8);

        // scores (swapped): C[m][n], lane: n = ln, m = mt*16 + kb*4 + i
        f32x4 c0 = (f32x4){0, 0, 0, 0}, c1 = (f32x4){0, 0, 0, 0};
        c0 = __builtin_amdgcn_mfma_f32_16x16x32_bf16(tb[0], sb0, c0, 0, 0, 0);
        c0 = __builtin_amdgcn_mfma_f32_16x16x32_bf16(tb[1], sb1, c0, 0, 0, 0);
        c1 = __builtin_amdgcn_mfma_f32_16x16x32_bf16(tb[2], sb0, c1, 0, 0, 0);
        c1 = __builtin_amdgcn_mfma_f32_16x16x32_bf16(tb[3], sb1, c1, 0, 0, 0);
        ushort4 a0 = av[0], a1 = av[1];

        // prefetch tgt/adj for chunk+2 into the same (now-consumed) buffers
        if (m0next < N_) loadT(m0next, tb, av);

        // mask + pack to bf16, write 8B per mt into wave-private LDS
        unsigned short* sp = sa_w + par * 576 + ln * 36;
        {
            uint2 q;
            q.x = (unsigned)f2bf_hw(fmaxf(c0[0], 0.f) * bf2f(a0.x))
                | ((unsigned)f2bf_hw(fmaxf(c0[1], 0.f) * bf2f(a0.y)) << 16);
            q.y = (unsigned)f2bf_hw(fmaxf(c0[2], 0.f) * bf2f(a0.z))
                | ((unsigned)f2bf_hw(fmaxf(c0[3], 0.f) * bf2f(a0.w)) << 16);
            *(uint2*)(sp + 0 * 16 + kb * 4) = q;
        }
        {
            uint2 q;
            q.x = (unsigned)f2bf_hw(fmaxf(c1[0], 0.f) * bf2f(a1.x))
                | ((unsigned)f2bf_hw(fmaxf(c1[1], 0.f) * bf2f(a1.y)) << 16);
            q.y = (unsigned)f2bf_hw(fmaxf(c1[2], 0.f) * bf2f(a1.z))
                | ((unsigned)f2bf_hw(fmaxf(c1[3], 0.f) * bf2f(a1.w)) << 16);
            *(uint2*)(sp + 1 * 16 + kb * 4) = q;
        }

        // conv A-frag: row n = ln, k(m) = kb*8 + j  (two 8B reads, 8B-aligned)
        union { short8 v; uint2 u[2]; } af;
        af.u[0] = *(const uint2*)(sp + kb * 8);
        af.u[1] = *(const uint2*)(sp + kb * 8 + 4);

        acc[0] = __builtin_amdgcn_mfma_f32_16x16x32_bf16(af.v, bs0, acc[0], 0, 0, 0);
        acc[1] = __builtin_amdgcn_mfma_f32_16x16x32_bf16(af.v, bs1, acc[1], 0, 0, 0);
        acc[2] = __builtin_amdgcn_mfma_f32_16x16x32_bf16(af.v, bs2, acc[2], 0, 0, 0);
        acc[3] = __builtin_amdgcn_mfma_f32_16x16x32_bf16(af.v, bs3, acc[3], 0, 0, 0);
    };

    short8 tbA[4], tbB[4];
    ushort4 avA[2], avB[2];
    loadT(0, tbA, avA);
    loadT(32, tbB, avB);

    for (int tt = 0; tt < 32; tt += 2) {
        chunk(tt * 32,       tbA, avA, 0, (tt + 2) * 32);
        chunk((tt + 1) * 32, tbB, avB, 1, (tt + 3) * 32);
    }

    // epilogue: out = relu(conv + bias + residual)
#pragma unroll
    for (int ft = 0; ft < 4; ++ft) {
        const int f = fh * 64 + ft * 16 + ln;
        const float bi = bias[f];
#pragma unroll
        for (int ii = 0; ii < 4; ++ii) {
            const int n = n0 + ns * 16 + kb * 4 + ii;
            const size_t o = ((size_t)b * N_ + n) * F_ + f;
            out[o] = fmaxf(acc[ft][ii] + bi + bf2f(resid[o]), 0.f);
        }
    }
}

// ---------------------------------------------------------------------------
extern "C" void kernel_launch(void* const* d_in, const int* in_sizes, int n_in,
                              void* d_out, int out_size, void* d_ws, size_t ws_size,
                              hipStream_t stream) {
    const float* input_features = (const float*)d_in[0];
    const int*   cycle_indices  = (const int*)  d_in[1];
    const float* weight         = (const float*)d_in[2];
    const float* bias           = (const float*)d_in[3];
    const float* src_emb        = (const float*)d_in[4];
    const float* tgt_emb        = (const float*)d_in[5];
    const float* env_W          = (const float*)d_in[6];
    const float* env_b          = (const float*)d_in[7];
    const float* res_W          = (const float*)d_in[8];
    const float* res_b          = (const float*)d_in[9];
    const float* static_adj     = (const float*)d_in[10];
    const float* env_features   = (const float*)d_in[11];
    float* out = (float*)d_out;

    // workspace layout (~25.2 MiB)
    char* wsb = (char*)d_ws;
    unsigned short* src_bf = (unsigned short*)wsb;               // 3145728 B
    unsigned short* tgt_bf = src_bf + (size_t)NPER * N_ * H_;    // 3145728 B
    unsigned short* Wt     = tgt_bf + (size_t)NPER * N_ * H_;    // 32768 B
    unsigned short* rWt    = Wt + 16384;                         // 32768 B
    unsigned short* supT   = rWt + 16384;                        // 8388608 B
    unsigned short* resid  = supT + (size_t)B_ * F_ * N_;        // 8388608 B
    unsigned short* adj_bf = resid + (size_t)B_ * N_ * F_;       // 2097152 B

    prep_srctgt<<<(N_ * H_) / 256, 256, 0, stream>>>(
        src_emb, tgt_emb, env_features, env_W, env_b, src_bf, tgt_bf);

    prep_cvt<<<1024 + 128, 256, 0, stream>>>(
        static_adj, weight, res_W, adj_bf, Wt, rWt);

    gemm2_mfma<<<(B_ * N_) / 32, 256, 0, stream>>>(
        input_features, Wt, rWt, res_b, supT, resid);

    conv_mfma<<<1024, 256, 0, stream>>>(
        src_bf, tgt_bf, adj_bf, supT, resid, bias, cycle_indices, out);
}

// Round 6
// 101.233 us; speedup vs baseline: 1.7805x; 1.7805x over previous
//
#include <hip/hip_runtime.h>
#include <hip/hip_bf16.h>

#define NPER 24
#define B_ 32
#define N_ 1024
#define F_ 128
#define H_ 64
#define E_ 16

typedef __attribute__((ext_vector_type(8))) short short8;
typedef __attribute__((ext_vector_type(4))) float f32x4;

static __device__ __forceinline__ unsigned short f2bf(float x) {
    union { float f; unsigned u; } v; v.f = x;
    unsigned r = v.u + 0x7fffu + ((v.u >> 16) & 1u);   // RNE
    return (unsigned short)(r >> 16);
}
static __device__ __forceinline__ float bf2f(unsigned short h) {
    union { unsigned u; float f; } v; v.u = ((unsigned)h) << 16; return v.f;
}
static __device__ __forceinline__ unsigned short f2bf_hw(float x) {
    __hip_bfloat16 h = __float2bfloat16(x);
    return *(unsigned short*)&h;
}

// ---------------------------------------------------------------------------
// P1: env encoder fused into src/tgt bf16 conversion for all 24 periods.
// ---------------------------------------------------------------------------
__global__ __launch_bounds__(256) void prep_srctgt(
    const float* __restrict__ src_emb, const float* __restrict__ tgt_emb,
    const float* __restrict__ env_features, const float* __restrict__ env_W,
    const float* __restrict__ env_b,
    unsigned short* __restrict__ src_bf, unsigned short* __restrict__ tgt_bf)
{
    const int idx = blockIdx.x * 256 + threadIdx.x;   // 0..65535
    const int n = idx >> 6, h = idx & 63;
    float e = env_b[h];
#pragma unroll
    for (int k = 0; k < E_; ++k)
        e = fmaf(env_features[n * E_ + k], env_W[k * H_ + h], e);
    e = fmaxf(e, 0.f);
#pragma unroll 4
    for (int p = 0; p < NPER; ++p) {
        const size_t off = (size_t)p * (N_ * H_) + idx;
        src_bf[off] = f2bf(src_emb[off] + e);
        tgt_bf[off] = f2bf(tgt_emb[off] + e);
    }
}

// ---------------------------------------------------------------------------
// P2: adj -> bf16 (blocks 0..1023) ; W/rW transpose -> bf16 (blocks 1024..1151)
// ---------------------------------------------------------------------------
__global__ __launch_bounds__(256) void prep_cvt(
    const float* __restrict__ adj, const float* __restrict__ W,
    const float* __restrict__ rW,
    unsigned short* __restrict__ adj_bf, unsigned short* __restrict__ Wt,
    unsigned short* __restrict__ rWt)
{
    const int bid = blockIdx.x;
    if (bid < 1024) {
        const size_t i = ((size_t)bid * 256 + threadIdx.x) * 4;
        float4 v = *(const float4*)(adj + i);
        ushort4 o;
        o.x = f2bf(v.x); o.y = f2bf(v.y); o.z = f2bf(v.z); o.w = f2bf(v.w);
        *(ushort4*)(adj_bf + i) = o;
    } else {
        const int idx = (bid - 1024) * 256 + threadIdx.x;   // 0..32767
        const int which = idx >> 14, j = idx & 16383;
        const int f = j >> 7, d = j & 127;
        if (which == 0) Wt[f * 128 + d]  = f2bf(W[d * 128 + f]);
        else            rWt[f * 128 + d] = f2bf(rW[d * 128 + f]);
    }
}

// ---------------------------------------------------------------------------
// K5: support^T (swapped GEMM) + residual, both bf16 out, MFMA. [verified]
// ---------------------------------------------------------------------------
__global__ __launch_bounds__(256) void gemm2_mfma(
    const float* __restrict__ x,               // [B*N][128] fp32
    const unsigned short* __restrict__ Wt,     // [128f][128d]
    const unsigned short* __restrict__ rWt,    // [128f][128d]
    const float* __restrict__ rb,              // [128]
    unsigned short* __restrict__ supT,         // [B][128f][1024m]
    unsigned short* __restrict__ resid)        // [B*N][128]
{
    const int t = threadIdx.x, w = t >> 6, l = t & 63;
    const int ln = l & 15, kb = l >> 4;
    const int mblk = w >> 1, fhalf = w & 1;
    const int row0 = blockIdx.x * 32;
    const int b   = row0 >> 10;
    const int mg0 = row0 & 1023;

    const float* xrow = x + (size_t)(row0 + mblk * 16 + ln) * 128;
    short8 xa[4];
#pragma unroll
    for (int k = 0; k < 4; ++k) {
        float4 v0 = *(const float4*)(xrow + k * 32 + kb * 8);
        float4 v1 = *(const float4*)(xrow + k * 32 + kb * 8 + 4);
        short8 s;
        s[0] = (short)f2bf(v0.x); s[1] = (short)f2bf(v0.y);
        s[2] = (short)f2bf(v0.z); s[3] = (short)f2bf(v0.w);
        s[4] = (short)f2bf(v1.x); s[5] = (short)f2bf(v1.y);
        s[6] = (short)f2bf(v1.z); s[7] = (short)f2bf(v1.w);
        xa[k] = s;
    }

    f32x4 accS[4], accR[4];
#pragma unroll
    for (int i = 0; i < 4; ++i) { accS[i] = (f32x4){0,0,0,0}; accR[i] = (f32x4){0,0,0,0}; }

#pragma unroll
    for (int k = 0; k < 4; ++k) {
#pragma unroll
        for (int fb = 0; fb < 4; ++fb) {
            int fr = (fhalf * 4 + fb) * 16 + ln;
            short8 wa = *(const short8*)(Wt  + (size_t)fr * 128 + k * 32 + kb * 8);
            short8 wb = *(const short8*)(rWt + (size_t)fr * 128 + k * 32 + kb * 8);
            accS[fb] = __builtin_amdgcn_mfma_f32_16x16x32_bf16(wa, xa[k], accS[fb], 0, 0, 0);
            accR[fb] = __builtin_amdgcn_mfma_f32_16x16x32_bf16(xa[k], wb, accR[fb], 0, 0, 0);
        }
    }

#pragma unroll
    for (int fb = 0; fb < 4; ++fb) {
        int m = mg0 + mblk * 16 + ln;
#pragma unroll
        for (int i = 0; i < 4; ++i) {
            int f = (fhalf * 4 + fb) * 16 + kb * 4 + i;
            supT[((size_t)b * 128 + f) * 1024 + m] = f2bf(accS[fb][i]);
        }
    }
#pragma unroll
    for (int fb = 0; fb < 4; ++fb) {
        int f = (fhalf * 4 + fb) * 16 + ln;
        float rbf = rb[f];
#pragma unroll
        for (int i = 0; i < 4; ++i) {
            size_t row = (size_t)row0 + mblk * 16 + kb * 4 + i;
            resid[row * 128 + f] = f2bf(fmaxf(accR[fb][i] + rbf, 0.f));
        }
    }
}

// ---------------------------------------------------------------------------
// K6: fused scores -> relu*adj -> conv -> epilogue.  (r4 structure, but
// T3/T4 sync: raw s_barrier + per-wave lgkmcnt(0) drain only — global
// prefetches stay in flight across barriers; sched_barrier(0) pins the
// load-issue cluster at the top of each sub-iteration.)
// Block = 32 n-rows, 256 threads / 4 waves, grid 1024 (chunked XCD swizzle).
// Score role: wave w -> n-tile sn=w>>1, m-pair sm=w&1.
// Conv role:  wave w -> 32-col f group cf=w.
// ---------------------------------------------------------------------------
__global__ __launch_bounds__(256, 4) void conv_mfma(
    const unsigned short* __restrict__ src_bf,  // [P][N][64]
    const unsigned short* __restrict__ tgt_bf,  // [P][N][64]
    const unsigned short* __restrict__ adj_bf,  // [N][N]
    const unsigned short* __restrict__ supT,    // [B][128][1024]
    const unsigned short* __restrict__ resid,   // [B*N][128]
    const float* __restrict__ bias,             // [128]
    const int* __restrict__ cyc,                // [B]
    float* __restrict__ out)                    // [B][N][128]
{
    __shared__ unsigned short s_a[2][32][72] __attribute__((aligned(16)));

    // chunked XCD swizzle (r4-verified: FETCH 48.9 -> 20.8 MB)
    const int i = blockIdx.x;                    // 0..1023
    const int work = (i & 7) * 128 + (i >> 3);
    const int b  = work >> 5;
    const int n0 = (work & 31) * 32;

    const int t = threadIdx.x, w = t >> 6, l = t & 63;
    const int ln = l & 15, kb = l >> 4;
    const int p = ((cyc[b] % NPER) + NPER) % NPER;

    const int sn = w >> 1, sm = w & 1;   // score role
    const int cf = w;                     // conv role

    const unsigned short* srow = src_bf + ((size_t)p * N_ + n0 + sn * 16 + ln) * H_;
    const short8 sa0 = *(const short8*)(srow + kb * 8);
    const short8 sa1 = *(const short8*)(srow + 32 + kb * 8);

    const unsigned short* tbase = tgt_bf + (size_t)p * N_ * H_;
    const unsigned short* supb  = supT + (size_t)b * (size_t)F_ * N_;

    f32x4 acc[2][2];
#pragma unroll
    for (int r = 0; r < 2; ++r)
#pragma unroll
        for (int fb = 0; fb < 2; ++fb) acc[r][fb] = (f32x4){0, 0, 0, 0};

    auto loadT = [&](int m0, short8 (&tb)[2][2], unsigned short (&av)[2][4]) {
#pragma unroll
        for (int mt = 0; mt < 2; ++mt) {
            const unsigned short* trow =
                tbase + (size_t)(m0 + (sm * 2 + mt) * 16 + ln) * H_;
            tb[mt][0] = *(const short8*)(trow + kb * 8);
            tb[mt][1] = *(const short8*)(trow + 32 + kb * 8);
            const int ml = (sm * 2 + mt) * 16 + ln;
#pragma unroll
            for (int ii = 0; ii < 4; ++ii)
                av[mt][ii] = adj_bf[(size_t)(n0 + sn * 16 + kb * 4 + ii) * N_ + m0 + ml];
        }
    };
    auto loadS = [&](int m0, short8 (&bs)[2][2]) {
#pragma unroll
        for (int ks = 0; ks < 2; ++ks)
#pragma unroll
            for (int fb = 0; fb < 2; ++fb)
                bs[ks][fb] = *(const short8*)(
                    supb + (size_t)(cf * 32 + fb * 16 + ln) * N_ + m0 + ks * 32 + kb * 8);
    };
    auto score = [&](const short8 (&tb)[2][2], const unsigned short (&av)[2][4], int wb) {
#pragma unroll
        for (int mt = 0; mt < 2; ++mt) {
            f32x4 c = (f32x4){0, 0, 0, 0};
            c = __builtin_amdgcn_mfma_f32_16x16x32_bf16(sa0, tb[mt][0], c, 0, 0, 0);
            c = __builtin_amdgcn_mfma_f32_16x16x32_bf16(sa1, tb[mt][1], c, 0, 0, 0);
            const int ml = (sm * 2 + mt) * 16 + ln;
#pragma unroll
            for (int ii = 0; ii < 4; ++ii) {
                float a2 = fmaxf(c[ii], 0.f) * bf2f(av[mt][ii]);
                s_a[wb][sn * 16 + kb * 4 + ii][ml] = f2bf_hw(a2);
            }
        }
    };
    auto conv = [&](int rb, const short8 (&bs)[2][2]) {
#pragma unroll
        for (int ks = 0; ks < 2; ++ks) {
            short8 af0 = *(const short8*)(&s_a[rb][ln][ks * 32 + kb * 8]);
            short8 af1 = *(const short8*)(&s_a[rb][16 + ln][ks * 32 + kb * 8]);
#pragma unroll
            for (int fb = 0; fb < 2; ++fb) {
                acc[0][fb] = __builtin_amdgcn_mfma_f32_16x16x32_bf16(af0, bs[ks][fb], acc[0][fb], 0, 0, 0);
                acc[1][fb] = __builtin_amdgcn_mfma_f32_16x16x32_bf16(af1, bs[ks][fb], acc[1][fb], 0, 0, 0);
            }
        }
    };

    // T4 barrier: LDS visibility only (per-wave lgkmcnt drain + raw barrier);
    // global loads are NOT drained — they stay in flight across the barrier.
    auto barrier_lds = []() {
        asm volatile("s_waitcnt lgkmcnt(0)" ::: "memory");
        __builtin_amdgcn_s_barrier();
    };

    short8 tbA[2][2], tbB[2][2];
    unsigned short adjA[2][4], adjB[2][4];
    short8 bsA[2][2], bsB[2][2];

    // prologue
    loadT(0, tbA, adjA);
    loadT(64, tbB, adjB);
    loadS(0, bsA);
    score(tbA, adjA, 0);
    barrier_lds();

    for (int tt = 0; tt < 16; tt += 2) {
        // sub-iter tt: conv chunk tt (bsA, buf0); score chunk tt+1 (tbB -> buf1)
        loadS((tt + 1) * 64, bsB);
        if (tt + 2 < 16) loadT((tt + 2) * 64, tbA, adjA);
        __builtin_amdgcn_sched_barrier(0);   // pin load issue before compute
        conv(0, bsA);
        score(tbB, adjB, 1);
        barrier_lds();

        // sub-iter tt+1: conv chunk tt+1 (bsB, buf1); score chunk tt+2 (tbA -> buf0)
        if (tt + 2 < 16) loadS((tt + 2) * 64, bsA);
        if (tt + 3 < 16) loadT((tt + 3) * 64, tbB, adjB);
        __builtin_amdgcn_sched_barrier(0);
        conv(1, bsB);
        if (tt + 2 < 16) {
            score(tbA, adjA, 0);
            barrier_lds();
        }
    }

    // epilogue: out = relu(conv + bias + residual)
#pragma unroll
    for (int r = 0; r < 2; ++r)
#pragma unroll
    for (int fb = 0; fb < 2; ++fb) {
        const int f = cf * 32 + fb * 16 + ln;
        const float bi = bias[f];
#pragma unroll
        for (int ii = 0; ii < 4; ++ii) {
            const int n = n0 + r * 16 + kb * 4 + ii;
            const size_t o = ((size_t)b * N_ + n) * F_ + f;
            out[o] = fmaxf(acc[r][fb][ii] + bi + bf2f(resid[o]), 0.f);
        }
    }
}

// ---------------------------------------------------------------------------
extern "C" void kernel_launch(void* const* d_in, const int* in_sizes, int n_in,
                              void* d_out, int out_size, void* d_ws, size_t ws_size,
                              hipStream_t stream) {
    const float* input_features = (const float*)d_in[0];
    const int*   cycle_indices  = (const int*)  d_in[1];
    const float* weight         = (const float*)d_in[2];
    const float* bias           = (const float*)d_in[3];
    const float* src_emb        = (const float*)d_in[4];
    const float* tgt_emb        = (const float*)d_in[5];
    const float* env_W          = (const float*)d_in[6];
    const float* env_b          = (const float*)d_in[7];
    const float* res_W          = (const float*)d_in[8];
    const float* res_b          = (const float*)d_in[9];
    const float* static_adj     = (const float*)d_in[10];
    const float* env_features   = (const float*)d_in[11];
    float* out = (float*)d_out;

    // workspace layout (~25.2 MiB)
    char* wsb = (char*)d_ws;
    unsigned short* src_bf = (unsigned short*)wsb;               // 3145728 B
    unsigned short* tgt_bf = src_bf + (size_t)NPER * N_ * H_;    // 3145728 B
    unsigned short* Wt     = tgt_bf + (size_t)NPER * N_ * H_;    // 32768 B
    unsigned short* rWt    = Wt + 16384;                         // 32768 B
    unsigned short* supT   = rWt + 16384;                        // 8388608 B
    unsigned short* resid  = supT + (size_t)B_ * F_ * N_;        // 8388608 B
    unsigned short* adj_bf = resid + (size_t)B_ * N_ * F_;       // 2097152 B

    prep_srctgt<<<(N_ * H_) / 256, 256, 0, stream>>>(
        src_emb, tgt_emb, env_features, env_W, env_b, src_bf, tgt_bf);

    prep_cvt<<<1024 + 128, 256, 0, stream>>>(
        static_adj, weight, res_W, adj_bf, Wt, rWt);

    gemm2_mfma<<<(B_ * N_) / 32, 256, 0, stream>>>(
        input_features, Wt, rWt, res_b, supT, resid);

    conv_mfma<<<1024, 256, 0, stream>>>(
        src_bf, tgt_bf, adj_bf, supT, resid, bias, cycle_indices, out);
}